// Round 4
// baseline (11.523 us; speedup 1.0000x reference)
//
#include <hip/hip_runtime.h>

// x: (8, 2, 512, 512) f32 ; out: (8, 2, 512, 512) f32
// W1,B1,W2,B2,W3: (4,16) f32 ; B3: (4,) f32
//
// grads[k](s) = A[k]*s^2 + B[k]*s + C[k]  (coefficients reduced over c,
// see R0 derivation); k=0,1 at s=u, k=2,3 at s=v.
// out_u = u*g0(u) + v*g1(u) ; out_v = u*g2(v) + v*g3(v)
//
// Single fused kernel, max-TLP variant: PER_THREAD=1, 2048 blocks ->
// 8 blocks/CU = 32 waves/CU (occupancy max) to deepen the request queue
// during the HBM latency ramp. Coefficients computed per-wave lane-parallel
// (lane = k*16+c) + shfl_xor butterfly; overlapped with the x loads.

#define BATCH  8
#define HW     (512 * 512)
#define HW4    (HW / 4)            // 65536 float4 per plane
#define TOTAL4 (BATCH * HW4)       // 524288 float4 groups per field
#define THREADS 256
#define BLOCKS  (TOTAL4 / THREADS)   // 2048

__global__ __launch_bounds__(THREADS) void percnn_fused_kernel(
        const float4* __restrict__ x,
        float4* __restrict__ out,
        const float* __restrict__ W1,
        const float* __restrict__ B1,
        const float* __restrict__ W2,
        const float* __restrict__ B2,
        const float* __restrict__ W3,
        const float* __restrict__ B3) {
    // ---- main-body addresses & loads FIRST (independent of coefficients) --
    const int idx = blockIdx.x * THREADS + threadIdx.x;
    const int b = idx >> 16;           // / HW4
    const int i = idx & (HW4 - 1);     // % HW4

    const size_t uoff = (size_t)(b * 2 + 0) * HW4 + i;
    const size_t voff = (size_t)(b * 2 + 1) * HW4 + i;

    const float4 u4 = x[uoff];
    const float4 v4 = x[voff];

    // ---- per-wave coefficient computation (lane = k*16 + c) ----
    const int lane = threadIdx.x & 63;
    const float w1 = W1[lane], bb1 = B1[lane];
    const float w2 = W2[lane], bb2 = B2[lane];
    const float w3 = W3[lane];

    float pA = w3 * w1 * w2;
    float pB = w3 * fmaf(w1, bb2, bb1 * w2);
    float pC = w3 * bb1 * bb2;

    #pragma unroll
    for (int off = 8; off >= 1; off >>= 1) {
        pA += __shfl_xor(pA, off);
        pB += __shfl_xor(pB, off);
        pC += __shfl_xor(pC, off);
    }
    const float A0 = __shfl(pA, 0),  A1 = __shfl(pA, 16);
    const float A2 = __shfl(pA, 32), A3 = __shfl(pA, 48);
    const float c10 = __shfl(pB, 0),  c11 = __shfl(pB, 16);
    const float c12 = __shfl(pB, 32), c13 = __shfl(pB, 48);
    const float c00 = __shfl(pC, 0)  + B3[0];
    const float c01 = __shfl(pC, 16) + B3[1];
    const float c02 = __shfl(pC, 32) + B3[2];
    const float c03 = __shfl(pC, 48) + B3[3];

    // ---- compute + store ----
    float4 ou, ov;
    #pragma unroll
    for (int j = 0; j < 4; ++j) {
        const float u = (&u4.x)[j];
        const float v = (&v4.x)[j];
        const float g0 = fmaf(fmaf(A0, u, c10), u, c00);
        const float g1 = fmaf(fmaf(A1, u, c11), u, c01);
        const float g2 = fmaf(fmaf(A2, v, c12), v, c02);
        const float g3 = fmaf(fmaf(A3, v, c13), v, c03);
        (&ou.x)[j] = fmaf(u, g0, v * g1);
        (&ov.x)[j] = fmaf(u, g2, v * g3);
    }

    out[uoff] = ou;
    out[voff] = ov;
}

extern "C" void kernel_launch(void* const* d_in, const int* in_sizes, int n_in,
                              void* d_out, int out_size, void* d_ws, size_t ws_size,
                              hipStream_t stream) {
    const float* x  = (const float*)d_in[0];
    const float* W1 = (const float*)d_in[1];
    const float* B1 = (const float*)d_in[2];
    const float* W2 = (const float*)d_in[3];
    const float* B2 = (const float*)d_in[4];
    const float* W3 = (const float*)d_in[5];
    const float* B3 = (const float*)d_in[6];
    float* out = (float*)d_out;

    percnn_fused_kernel<<<BLOCKS, THREADS, 0, stream>>>(
        (const float4*)x, (float4*)out, W1, B1, W2, B2, W3, B3);
}